// Round 3
// baseline (221.453 us; speedup 1.0000x reference)
//
#include <hip/hip_runtime.h>
#include <hip/hip_bf16.h>

#define KOFF 27
#define C 64
#define RPB 128          // rows per block
#define EPS 1e-5f

typedef __attribute__((ext_vector_type(8))) short short8;
typedef __attribute__((ext_vector_type(4))) float f32x4;

__device__ inline unsigned short f2bf(float x) {
    __hip_bfloat16 h = __float2bfloat16(x);
    unsigned short u;
    __builtin_memcpy(&u, &h, 2);
    return u;
}

// ---- pre-pass 1: feats fp32 -> bf16 ----
__global__ void cvt_feats(const float* __restrict__ in, unsigned short* __restrict__ o, int n4) {
    int i = blockIdx.x * blockDim.x + threadIdx.x;
    if (i < n4) {
        float4 v = ((const float4*)in)[i];
        ushort4 u;
        u.x = f2bf(v.x); u.y = f2bf(v.y); u.z = f2bf(v.z); u.w = f2bf(v.w);
        ((ushort4*)o)[i] = u;
    }
}

// ---- pre-pass 2: W_conv -> fragment-order bf16 (lane-contiguous 16B per B-frag);
//      W_lin -> [d][c] bf16; zero-page ----
__global__ void cvt_w(const float* __restrict__ Wc, const float* __restrict__ Wl,
                      unsigned short* __restrict__ WcF, unsigned short* __restrict__ WlT,
                      unsigned short* __restrict__ Z) {
    int i = blockIdx.x * blockDim.x + threadIdx.x;
    const int NWc = KOFF * 4096;
    if (i < NWc) {
        // layout: [ko][t][ks][lane][j], 8 shorts per lane (=16B)
        int ko = i >> 12;
        int rem = i & 4095;
        int t = rem >> 10;
        int ks = (rem >> 9) & 1;
        int l = (rem >> 3) & 63;
        int j = i & 7;
        int c = ks * 32 + ((l >> 4) << 3) + j;   // B-frag k index
        int d = (t << 4) + (l & 15);             // B-frag n index
        WcF[i] = f2bf(Wc[(ko << 12) + (c << 6) + d]);
    } else if (i < NWc + 4096) {
        int j = i - NWc;
        int d = j >> 6;
        int kk = j & 63;
        WlT[j] = f2bf(Wl[(kk << 6) + d]);
    } else if (i < NWc + 4096 + 128) {
        Z[i - NWc - 4096] = 0;
    }
}

struct SMem {
    union {
        int nb_tmp[RPB * KOFF];      // 13824 B, live during build
        float acc[129][68];          // 35088 B, live after (row 128 = pad dump)
    } u;
    int list[KOFF][RPB];             // packed (r<<20)|gidx
    int table[224];                  // packed (ko<<8)|slot0
    int cnt[KOFF];
    int T;
};

__launch_bounds__(256)
__global__ void conv_fused(const unsigned short* __restrict__ feats,
                           const int* __restrict__ nb,
                           const float* __restrict__ b_conv,
                           const float* __restrict__ b_lin,
                           const float* __restrict__ gamma,
                           const float* __restrict__ beta,
                           const unsigned short* __restrict__ WcF,
                           const unsigned short* __restrict__ WlT,
                           const unsigned short* __restrict__ zpage,
                           float* __restrict__ out, int nvox) {
    __shared__ SMem sm;
    const int tid = threadIdx.x;
    const int lane = tid & 63;
    const int wave = tid >> 6;
    const int m = lane & 15;
    const int krow = lane >> 4;
    const int coff = krow * 8;
    const int row0 = blockIdx.x * RPB;

    // ---- stage neighbor table (flat, coalesced) ----
    {
        const long gbase = (long)row0 * KOFF;
        const long glim = (long)nvox * KOFF;
        for (int j = tid; j < RPB * KOFF; j += 256) {
            long g = gbase + j;
            sm.u.nb_tmp[j] = (g < glim) ? nb[g] : -1;
        }
    }
    __syncthreads();

    // ---- build compacted per-offset lists (ballot prefix) ----
    for (int ko = wave; ko < KOFF; ko += 4) {
        int base = 0;
#pragma unroll
        for (int chunk = 0; chunk < 2; ++chunk) {
            int r = chunk * 64 + lane;
            int g = sm.u.nb_tmp[r * KOFF + ko];   // stride-27 ints: conflict-free
            unsigned long long msk = __ballot(g >= 0);
            int pre = __popcll(msk & ((1ull << lane) - 1));
            if (g >= 0) sm.list[ko][base + pre] = (r << 20) | g;
            base += __popcll(msk);
        }
        if (lane == 0) sm.cnt[ko] = base;
    }
    __syncthreads();

    // ---- zero accumulator; thread 0 builds tile table ----
    for (int j = tid; j < 129 * 68; j += 256) ((float*)sm.u.acc)[j] = 0.f;
    if (tid == 0) {
        int T = 0;
        for (int ko = 0; ko < KOFF; ++ko)
            for (int s = 0; s < sm.cnt[ko]; s += 16)
                sm.table[T++] = (ko << 8) | s;
        sm.T = T;
    }
    __syncthreads();

    // ---- main: compacted tiles, barrier-free, scatter-add into LDS f32 ----
    const int T = sm.T;
    for (int s = wave; s < T; s += 4) {
        int e = sm.table[s];
        int ko = e >> 8;
        int s0 = e & 255;
        int cnt = sm.cnt[ko];

        // A fragment: 16 compacted rows, zero-page for pad slots
        int slot = s0 + m;
        int pk = (slot < cnt) ? sm.list[ko][slot] : -1;
        const unsigned short* pa =
            (pk >= 0) ? feats + ((size_t)(pk & 0xFFFFF) << 6) : zpage;
        short8 a0 = *(const short8*)(pa + coff);
        short8 a1 = *(const short8*)(pa + 32 + coff);

        // scatter targets (output row = krow*4+i within tile)
        int rr[4];
#pragma unroll
        for (int i = 0; i < 4; ++i) {
            int so = s0 + krow * 4 + i;
            rr[i] = (so < cnt) ? (sm.list[ko][so] >> 20) : 128;
        }

        // B fragments: fragment-order layout, fully coalesced 1KB loads
        const unsigned short* w = WcF + ((size_t)ko << 12) + lane * 8;
        f32x4 c4[4];
#pragma unroll
        for (int t = 0; t < 4; ++t) {
            short8 b0 = *(const short8*)(w + t * 1024);
            short8 b1 = *(const short8*)(w + t * 1024 + 512);
            c4[t] = (f32x4){0.f, 0.f, 0.f, 0.f};
            c4[t] = __builtin_amdgcn_mfma_f32_16x16x32_bf16(a0, b0, c4[t], 0, 0, 0);
            c4[t] = __builtin_amdgcn_mfma_f32_16x16x32_bf16(a1, b1, c4[t], 0, 0, 0);
        }

#pragma unroll
        for (int t = 0; t < 4; ++t)
#pragma unroll
            for (int i = 0; i < 4; ++i)
                atomicAdd(&sm.u.acc[rr[i]][t * 16 + m], c4[t][i]);
    }
    __syncthreads();

    // ---- epilogue: X = acc + b_conv (bf16), linear MFMA, LayerNorm ----
    float bl[4], g4[4], bt[4];
#pragma unroll
    for (int t = 0; t < 4; ++t) {
        int col = t * 16 + m;
        bl[t] = b_lin[col];
        g4[t] = gamma[col];
        bt[t] = beta[col];
    }

    const int r0 = wave * 32 + m;
    const int r1 = r0 + 16;
    auto mk = [&](int r, int ks) -> short8 {
        const float* px = &sm.u.acc[r][ks * 32 + coff];
        float4 x0 = *(const float4*)px;
        float4 x1 = *(const float4*)(px + 4);
        float4 b0 = *(const float4*)(b_conv + ks * 32 + coff);
        float4 b1 = *(const float4*)(b_conv + ks * 32 + coff + 4);
        short8 v;
        v[0] = (short)f2bf(x0.x + b0.x); v[1] = (short)f2bf(x0.y + b0.y);
        v[2] = (short)f2bf(x0.z + b0.z); v[3] = (short)f2bf(x0.w + b0.w);
        v[4] = (short)f2bf(x1.x + b1.x); v[5] = (short)f2bf(x1.y + b1.y);
        v[6] = (short)f2bf(x1.z + b1.z); v[7] = (short)f2bf(x1.w + b1.w);
        return v;
    };
    short8 xa00 = mk(r0, 0), xa01 = mk(r0, 1);
    short8 xa10 = mk(r1, 0), xa11 = mk(r1, 1);

    f32x4 d0[4], d1[4];
#pragma unroll
    for (int t = 0; t < 4; ++t) {
        d0[t] = (f32x4){0.f, 0.f, 0.f, 0.f};
        d1[t] = (f32x4){0.f, 0.f, 0.f, 0.f};
    }
#pragma unroll
    for (int t = 0; t < 4; ++t) {
        short8 wb0 = *(const short8*)(WlT + (t * 16 + m) * 64 + coff);
        short8 wb1 = *(const short8*)(WlT + (t * 16 + m) * 64 + 32 + coff);
        d0[t] = __builtin_amdgcn_mfma_f32_16x16x32_bf16(xa00, wb0, d0[t], 0, 0, 0);
        d0[t] = __builtin_amdgcn_mfma_f32_16x16x32_bf16(xa01, wb1, d0[t], 0, 0, 0);
        d1[t] = __builtin_amdgcn_mfma_f32_16x16x32_bf16(xa10, wb0, d1[t], 0, 0, 0);
        d1[t] = __builtin_amdgcn_mfma_f32_16x16x32_bf16(xa11, wb1, d1[t], 0, 0, 0);
    }

#pragma unroll
    for (int rb = 0; rb < 2; ++rb) {
        f32x4* d = rb ? d1 : d0;
        float s1[4], s2[4];
#pragma unroll
        for (int i = 0; i < 4; ++i) {
            float a0 = d[0][i] + bl[0];
            float a1 = d[1][i] + bl[1];
            float a2 = d[2][i] + bl[2];
            float a3 = d[3][i] + bl[3];
            d[0][i] = a0; d[1][i] = a1; d[2][i] = a2; d[3][i] = a3;
            s1[i] = a0 + a1 + a2 + a3;
            s2[i] = a0 * a0 + a1 * a1 + a2 * a2 + a3 * a3;
        }
#pragma unroll
        for (int msk = 1; msk < 16; msk <<= 1) {
#pragma unroll
            for (int i = 0; i < 4; ++i) {
                s1[i] += __shfl_xor(s1[i], msk, 64);
                s2[i] += __shfl_xor(s2[i], msk, 64);
            }
        }
#pragma unroll
        for (int i = 0; i < 4; ++i) {
            float mu = s1[i] * (1.f / 64.f);
            float var = s2[i] * (1.f / 64.f) - mu * mu;
            float rs = rsqrtf(var + EPS);
            int grow = row0 + wave * 32 + rb * 16 + krow * 4 + i;
            if (grow < nvox) {
#pragma unroll
                for (int t = 0; t < 4; ++t) {
                    out[(size_t)grow * 64 + t * 16 + m] = g4[t] * (d[t][i] - mu) * rs + bt[t];
                }
            }
        }
    }
}

extern "C" void kernel_launch(void* const* d_in, const int* in_sizes, int n_in,
                              void* d_out, int out_size, void* d_ws, size_t ws_size,
                              hipStream_t stream) {
    const float* feats = (const float*)d_in[0];
    const int* nb = (const int*)d_in[1];
    const float* Wc = (const float*)d_in[2];
    const float* b_conv = (const float*)d_in[3];
    const float* Wl = (const float*)d_in[4];
    const float* b_lin = (const float*)d_in[5];
    const float* gamma = (const float*)d_in[6];
    const float* beta = (const float*)d_in[7];
    float* out = (float*)d_out;

    const int nvox = in_sizes[0] / C;

    unsigned short* feats_bf = (unsigned short*)d_ws;
    unsigned short* WcF = feats_bf + (size_t)nvox * C;
    unsigned short* WlT = WcF + KOFF * 4096;
    unsigned short* Z = WlT + 4096;

    int n4 = (nvox * C) / 4;
    cvt_feats<<<(n4 + 255) / 256, 256, 0, stream>>>(feats, feats_bf, n4);

    int nw = KOFF * 4096 + 4096 + 128;
    cvt_w<<<(nw + 255) / 256, 256, 0, stream>>>(Wc, Wl, WcF, WlT, Z);

    int nblk = (nvox + RPB - 1) / RPB;
    conv_fused<<<nblk, 256, 0, stream>>>(feats_bf, nb, b_conv, b_lin, gamma, beta,
                                         WcF, WlT, Z, out, nvox);
}